// Round 7
// baseline (745.354 us; speedup 1.0000x reference)
//
#include <hip/hip_runtime.h>

#define N_NODES   20000
#define N_EDGES   200000
#define EDGE_DIM  16
#define N_GRAPHS  64

// ===========================================================================
// CSR build (tgt-CSR with edge ids + pre-gathered src ids)
// ===========================================================================

__global__ __launch_bounds__(256) void build_deg_kernel(
    const int* __restrict__ tgts, int* __restrict__ deg)
{
    int e = blockIdx.x * blockDim.x + threadIdx.x;
    if (e >= N_EDGES) return;
    atomicAdd(deg + tgts[e], 1);
}

__global__ __launch_bounds__(256) void scan_deg_kernel(
    const int* __restrict__ deg, int* __restrict__ start, int* __restrict__ cursor)
{
    __shared__ int partial[256];
    const int C = (N_NODES + 255) / 256;   // 79
    int t  = threadIdx.x;
    int lo = t * C;
    int hi = lo + C < N_NODES ? lo + C : N_NODES;
    int s = 0;
    for (int i = lo; i < hi; ++i) s += deg[i];
    partial[t] = s;
    __syncthreads();
    if (t == 0) {
        int run = 0;
        for (int i = 0; i < 256; ++i) { int v = partial[i]; partial[i] = run; run += v; }
    }
    __syncthreads();
    int run = partial[t];
    for (int i = lo; i < hi; ++i) {
        start[i]  = run;
        cursor[i] = run;
        run += deg[i];
    }
    if (lo < N_NODES && hi == N_NODES) start[N_NODES] = run;
}

__global__ __launch_bounds__(256) void scatter_kernel(
    const int* __restrict__ tgts, const int* __restrict__ srcs,
    int* __restrict__ cursor, int* __restrict__ eid_t, int* __restrict__ src_t)
{
    int e = blockIdx.x * blockDim.x + threadIdx.x;
    if (e >= N_EDGES) return;
    int p = atomicAdd(cursor + tgts[e], 1);
    eid_t[p] = e;
    src_t[p] = srcs[e];
}

// ===========================================================================
// znn_conv: one 32-lane group per target node (8 groups / 256-block, no
// __syncthreads anywhere -- groups fully independent).
//   Edge phase (lane l = k-role, also i-role for staging):
//     Z[l][i] += h_l * x[src][i]   (Z-row in 32 regs; x, ea broadcast via LDS)
//     S_l     += x[src][l]
//   Contraction (lane l owns W2 row l, b2 row l, root row l):
//     contrib[o] = sum_i Z[l][i]*W2[l][i*32+o] + S_l*b2[l*32+o]
//                + max(d,1)*feat[v][l]*root[l*32+o]
//   Reduce over lanes via XOR-swizzled LDS transpose (write 4-way, read clean)
//   out[v][o=l] = relu(colsum/max(d,1) + bias[l])   [+ optional pool atomics]
// ===========================================================================
__global__ __launch_bounds__(256) void znn_conv_kernel(
    const float* __restrict__ feat,    // [N][32]
    const float* __restrict__ ea,      // [E][16]
    const int*   __restrict__ start_t, // [N+1]
    const int*   __restrict__ eid_t,   // [E]
    const int*   __restrict__ src_t,   // [E]
    const float* __restrict__ W1,      // [16][32]
    const float* __restrict__ b1,      // [32]
    const float* __restrict__ W2,      // [32][1024]
    const float* __restrict__ b2,      // [1024]
    const float* __restrict__ root,    // [32][32]
    const float* __restrict__ bias,    // [32]
    float*       __restrict__ outf,    // [N][32] or null
    const int*   __restrict__ batch,   // [N] or null
    float*       __restrict__ pool,    // [G][32]
    float*       __restrict__ pcnt)    // [G]
{
    __shared__ __align__(16) float LDSc[8][1024];  // 32 KB transpose buffer
    __shared__ __align__(16) float Xs[8][32];
    __shared__ __align__(16) float EAs[8][16];

    int tid = threadIdx.x;
    int g = tid >> 5;
    int l = tid & 31;
    int v = blockIdx.x * 8 + g;        // grid = 2500 blocks -> v < 20000 exactly

    // per-lane W1 column + b1 (k = l)
    float w1c[EDGE_DIM];
    #pragma unroll
    for (int j = 0; j < EDGE_DIM; ++j) w1c[j] = W1[j * 32 + l];
    float b1v = b1[l];

    float z[32];
    #pragma unroll
    for (int i = 0; i < 32; ++i) z[i] = 0.f;
    float S = 0.f;

    int j0 = start_t[v], j1 = start_t[v + 1];

    for (int j = j0; j < j1; ++j) {
        int e = eid_t[j];                          // group-uniform (broadcast)
        int s = src_t[j];                          // group-uniform, independent of e
        float xv = feat[(size_t)s * 32 + l];       // coalesced 128B per group
        float av = ea[(size_t)e * 16 + (l & 15)];  // coalesced 64B
        Xs[g][l] = xv;
        EAs[g][l & 15] = av;                       // dup writes same value, ok
        S += xv;

        // h for k = l
        float hv = b1v;
        #pragma unroll
        for (int jq = 0; jq < 4; ++jq) {
            float4 a4 = *reinterpret_cast<const float4*>(&EAs[g][jq * 4]);
            hv += a4.x * w1c[jq*4+0] + a4.y * w1c[jq*4+1]
                + a4.z * w1c[jq*4+2] + a4.w * w1c[jq*4+3];
        }
        hv = fmaxf(hv, 0.f);

        // Z-row update: z[i] += h * x[i] (broadcast reads)
        #pragma unroll
        for (int iq = 0; iq < 8; ++iq) {
            float4 x4 = *reinterpret_cast<const float4*>(&Xs[g][iq * 4]);
            z[iq*4+0] += hv * x4.x; z[iq*4+1] += hv * x4.y;
            z[iq*4+2] += hv * x4.z; z[iq*4+3] += hv * x4.w;
        }
    }

    // -------- contraction: lane l owns W2 row l --------
    float contrib[32];
    #pragma unroll
    for (int o = 0; o < 32; ++o) contrib[o] = 0.f;

    const float* wk = W2 + (size_t)l * 1024;
    #pragma unroll
    for (int i = 0; i < 32; ++i) {
        float zi = z[i];
        #pragma unroll
        for (int oq = 0; oq < 8; ++oq) {
            float4 w4 = *reinterpret_cast<const float4*>(wk + i * 32 + oq * 4);
            contrib[oq*4+0] += zi * w4.x; contrib[oq*4+1] += zi * w4.y;
            contrib[oq*4+2] += zi * w4.z; contrib[oq*4+3] += zi * w4.w;
        }
    }

    // fold b2 term (S * b2 row l) and root term (md * feat[v][l] * root row l)
    int d = j1 - j0;
    float md = (float)(d > 0 ? d : 1);
    float ft = feat[(size_t)v * 32 + l];
    float c2 = md * ft;
    const float* bp = b2   + (size_t)l * 32;
    const float* rp = root + (size_t)l * 32;
    #pragma unroll
    for (int oq = 0; oq < 8; ++oq) {
        float4 b4 = *reinterpret_cast<const float4*>(bp + oq * 4);
        float4 r4 = *reinterpret_cast<const float4*>(rp + oq * 4);
        contrib[oq*4+0] += S * b4.x + c2 * r4.x;
        contrib[oq*4+1] += S * b4.y + c2 * r4.y;
        contrib[oq*4+2] += S * b4.z + c2 * r4.z;
        contrib[oq*4+3] += S * b4.w + c2 * r4.w;
    }

    // -------- transpose-reduce across the 32 lanes (XOR swizzle) --------
    // logical quad q of lane l stored at physical quad q^(l&7)
    #pragma unroll
    for (int q = 0; q < 8; ++q) {
        int pq = q ^ (l & 7);
        float4 t;
        t.x = contrib[q*4+0]; t.y = contrib[q*4+1];
        t.z = contrib[q*4+2]; t.w = contrib[q*4+3];
        *reinterpret_cast<float4*>(&LDSc[g][l * 32 + pq * 4]) = t;
    }
    // element (k, o=l) lives at k*32 + ((l>>2)^(k&7))*4 + (l&3)
    int oq = l >> 2, oc = l & 3;
    float colsum = 0.f;
    #pragma unroll
    for (int k = 0; k < 32; ++k) {
        colsum += LDSc[g][k * 32 + (((oq ^ (k & 7)) << 2) | oc)];
    }

    float val = colsum / md + bias[l];
    val = fmaxf(val, 0.f);

    if (outf) outf[(size_t)v * 32 + l] = val;
    if (batch) {
        int gr = batch[v];
        atomicAdd(pool + (size_t)gr * 32 + l, val);
        if (l == 0) atomicAdd(pcnt + gr, 1.0f);
    }
}

// ===========================================================================
__global__ void head_kernel(
    const float* __restrict__ pool, const float* __restrict__ pcnt,
    const float* __restrict__ fcW, const float* __restrict__ fcb,
    float* __restrict__ out)
{
    int g = threadIdx.x;
    if (g >= N_GRAPHS) return;
    float inv = 1.0f / fmaxf(pcnt[g], 1.0f);
    float o0 = fcb[0], o1 = fcb[1];
    #pragma unroll
    for (int i = 0; i < 32; ++i) {
        float m = pool[g * 32 + i] * inv;
        o0 += m * fcW[i * 2 + 0];
        o1 += m * fcW[i * 2 + 1];
    }
    out[g * 2 + 0] = o0;
    out[g * 2 + 1] = o1;
}

// ===========================================================================

extern "C" void kernel_launch(void* const* d_in, const int* in_sizes, int n_in,
                              void* d_out, int out_size, void* d_ws, size_t ws_size,
                              hipStream_t stream)
{
    const float* x      = (const float*)d_in[0];
    const float* ea     = (const float*)d_in[1];
    const int*   ei     = (const int*)d_in[2];   // [2][E]
    const int*   batch  = (const int*)d_in[3];
    const float* en1_W1 = (const float*)d_in[4];
    const float* en1_b1 = (const float*)d_in[5];
    const float* en1_W2 = (const float*)d_in[6];
    const float* en1_b2 = (const float*)d_in[7];
    const float* root1  = (const float*)d_in[8];
    const float* bias1  = (const float*)d_in[9];
    const float* en2_W1 = (const float*)d_in[10];
    const float* en2_b1 = (const float*)d_in[11];
    const float* en2_W2 = (const float*)d_in[12];
    const float* en2_b2 = (const float*)d_in[13];
    const float* root2  = (const float*)d_in[14];
    const float* bias2  = (const float*)d_in[15];
    const float* fcW    = (const float*)d_in[16];
    const float* fcb    = (const float*)d_in[17];

    const int* srcs = ei;
    const int* tgts = ei + N_EDGES;

    dim3 eb(256), eg((N_EDGES + 255) / 256);

    // workspace layout (words):
    // zeroed: [deg N][pool G*32][pcnt G]
    // then:   [start N+2][cursor N][eid_t E][src_t E][h1 32N]
    int*   deg    = (int*)d_ws;
    float* pool   = (float*)(deg + N_NODES);
    float* pcnt   = pool + (size_t)N_GRAPHS * 32;
    int*   start  = (int*)(pcnt + N_GRAPHS);
    int*   cursor = start + (N_NODES + 2);
    int*   eid_t  = cursor + N_NODES;
    int*   src_t  = eid_t + N_EDGES;
    float* h1     = (float*)(src_t + N_EDGES);
    size_t zeroBytes = ((size_t)N_NODES + N_GRAPHS * 32 + N_GRAPHS) * sizeof(float);

    hipMemsetAsync(d_ws, 0, zeroBytes, stream);

    build_deg_kernel<<<eg, eb, 0, stream>>>(tgts, deg);
    scan_deg_kernel<<<dim3(1), dim3(256), 0, stream>>>(deg, start, cursor);
    scatter_kernel<<<eg, eb, 0, stream>>>(tgts, srcs, cursor, eid_t, src_t);

    const int NB = N_NODES / 8;   // 2500 blocks, 8 targets each

    // conv1: feat = x -> h1
    znn_conv_kernel<<<dim3(NB), dim3(256), 0, stream>>>(
        x, ea, start, eid_t, src_t,
        en1_W1, en1_b1, en1_W2, en1_b2, root1, bias1,
        h1, nullptr, nullptr, nullptr);

    // conv2: feat = h1 -> pool/pcnt (batch mean-pool fused)
    znn_conv_kernel<<<dim3(NB), dim3(256), 0, stream>>>(
        h1, ea, start, eid_t, src_t,
        en2_W1, en2_b1, en2_W2, en2_b2, root2, bias2,
        nullptr, batch, pool, pcnt);

    head_kernel<<<dim3(1), dim3(64), 0, stream>>>(pool, pcnt, fcW, fcb, (float*)d_out);
}